// Round 14
// baseline (247.465 us; speedup 1.0000x reference)
//
#include <hip/hip_runtime.h>
#include <hip/hip_bf16.h>

// ---------------------------------------------------------------------------
// SpatialAttention — ROUND 23 (= R22 + R18 VALU-diet on grid-768 attn +
// 32-way stats shards).
//  * R22 confirmed the atomic-tail theory: sharding 8-ways bought -35us with
//    busy counters unchanged. Push to 32 shards (chain 48 -> 12/address).
//  * k_attn: re-apply R18's proven VALU diet (wordmask AND via Mx + softmax
//    denominator on the MFMA pipe) on the grid-768 structure whose residency
//    problems made R18 dur-flat. Masking: 8 v_and_b32/chunk; denominator:
//    lacc = MFMA(ones,P,lacc), lane-local (no epilogue shuffles).
//  * GEMMs/k_norm_kv/k_norm_o = R22 (depth-3 counted vmcnt, 128x128).
//  * R12 lesson kept: NO second __launch_bounds__ arg on k_attn.
// Sizes: BT=96, N=512, D=128, heads=4, hd=32, RR=49152. Biases cancel in BN.
// ---------------------------------------------------------------------------

#define BT   96
#define NN   512
#define DD   128
#define CIN  256
#define CQKV 384
#define RR   49152
#define EPSB 1e-5f
#define K2E  0.7213475204444817f   // 0.5 * log2(e)
#define NSH  32                    // stats shards

using bf16  = __hip_bfloat16;
using bf8_t = __attribute__((ext_vector_type(8))) short;   // 8 x bf16
using f32x4 = __attribute__((ext_vector_type(4))) float;
using u32x4 = __attribute__((ext_vector_type(4))) unsigned int;

#define MFMA16(a,b,c) __builtin_amdgcn_mfma_f32_16x16x32_bf16((a),(b),(c),0,0,0)

__device__ __forceinline__ short f2b(float f) {
  bf16 h = __float2bfloat16(f);
  return *reinterpret_cast<short*>(&h);
}
__device__ __forceinline__ float b2f(short s) {
  bf16 h; *reinterpret_cast<short*>(&h) = s;
  return __bfloat162float(h);
}
__device__ __forceinline__ float fexp2(float x) {
#if __has_builtin(__builtin_amdgcn_exp2f)
  return __builtin_amdgcn_exp2f(x);
#else
  return exp2f(x);
#endif
}
__device__ __forceinline__ unsigned int pk2(float lo, float hi) {
  return (unsigned int)(unsigned short)f2b(lo) |
         ((unsigned int)(unsigned short)f2b(hi) << 16);
}
__device__ __forceinline__ void gl_lds16(const void* g, void* l) {
  __builtin_amdgcn_global_load_lds(
      (const __attribute__((address_space(1))) unsigned int*)g,
      (__attribute__((address_space(3))) unsigned int*)l, 16, 0, 0);
}

// ------------------- prep: Wt + Mx wordmasks + zero stats + X||STE cvt -----
// Items: 98304 (Wtq) + 16384 (Wto) + 16384 (Mx rows) + 32768 (st) +
// 1572864 (cvt) = 1736704 -> grid 6784 x 256.
// Mx row j: lane=j&63, c=(j>>6)&7, nt=j>>9. 16 shorts; element e of half h:
// mt=h*2+(e>>2), rr=e&3, key=(c*4+mt)*16+(lane>>4)*4+rr, query=nt*16+(lane&15);
// val = Am[query][key]>0 ? 0xFFFF : 0.
__global__ __launch_bounds__(256) void k_prep(
    const float* __restrict__ Wq, const float* __restrict__ Wk,
    const float* __restrict__ Wv, const float* __restrict__ Wo,
    const float* __restrict__ Am, const float* __restrict__ X,
    const float* __restrict__ STE,
    bf16* __restrict__ Wtq, bf16* __restrict__ Wto,
    short* __restrict__ Mx, float* __restrict__ st,
    bf16* __restrict__ Xb)
{
  int idx = blockIdx.x * 256 + threadIdx.x;
  if (idx < CQKV * CIN) {                          // Wtq[c][k] = W[k][c]
    int c = idx >> 8;
    int k = idx & 255;
    const float* W = (c < 128) ? Wq : ((c < 256) ? Wk : Wv);
    int cl = c & 127;
    Wtq[idx] = __float2bfloat16(W[(size_t)k * 128 + cl]);
  } else if (idx < CQKV * CIN + 128 * 128) {       // Wto[c][k] = Wo[k][c]
    int j = idx - CQKV * CIN;
    int c = j >> 7, k = j & 127;
    Wto[j] = __float2bfloat16(Wo[(size_t)k * 128 + c]);
  } else if (idx < CQKV * CIN + 128 * 128 + 16384) {  // Mx wordmask rows
    int j = idx - (CQKV * CIN + 128 * 128);
    int lane = j & 63, c = (j >> 6) & 7, nt = j >> 9;
    int quad = lane >> 4, l16 = lane & 15;
    int query = nt * 16 + l16;
    bf8_t m0, m1;
#pragma unroll
    for (int e = 0; e < 8; ++e) {
      int mt = e >> 2, rr = e & 3;
      int key = (c * 4 + mt) * 16 + quad * 4 + rr;
      m0[e] = (Am[(size_t)query * NN + key] > 0.f) ? (short)0xFFFF : (short)0;
    }
#pragma unroll
    for (int e = 0; e < 8; ++e) {
      int mt = 2 + (e >> 2), rr = e & 3;
      int key = (c * 4 + mt) * 16 + quad * 4 + rr;
      m1[e] = (Am[(size_t)query * NN + key] > 0.f) ? (short)0xFFFF : (short)0;
    }
    *reinterpret_cast<bf8_t*>(Mx + (size_t)j * 16)     = m0;
    *reinterpret_cast<bf8_t*>(Mx + (size_t)j * 16 + 8) = m1;
  } else if (idx < CQKV * CIN + 128 * 128 + 16384 + NSH * 1024) {
    st[idx - (CQKV * CIN + 128 * 128 + 16384)] = 0.f;
  } else {                                         // X||STE -> bf16 Xb
    int j = idx - (CQKV * CIN + 128 * 128 + 16384 + NSH * 1024);
    int row = j >> 5, cg = j & 31;                 // 8 cols per thread
    const float* src = (cg < 16) ? (X + (size_t)row * 128 + cg * 8)
                                 : (STE + (size_t)row * 128 + (cg - 16) * 8);
    f32x4 a = *reinterpret_cast<const f32x4*>(src);
    f32x4 b = *reinterpret_cast<const f32x4*>(src + 4);
    bf8_t o = bf8_t{ f2b(a[0]), f2b(a[1]), f2b(a[2]), f2b(a[3]),
                     f2b(b[0]), f2b(b[1]), f2b(b[2]), f2b(b[3]) };
    *reinterpret_cast<bf8_t*>(Xb + (size_t)row * 256 + cg * 8) = o;
  }
}

// ------------------- QKV GEMM + fused stats (depth-3 vmcnt pipeline) -------
// grid (384,3); 128x128 tile, BK=32, 8 k-steps, 3 LDS buffers (48 KB).
// Stats atomics sharded 32-ways by blockIdx.x to break L2 address chains.
__global__ __launch_bounds__(256) void k_gemm_qkv(
    const bf16* __restrict__ Xb, const bf16* __restrict__ Wt,
    bf16* __restrict__ Y, float* __restrict__ st)
{
  __shared__ __align__(16) bf16 As[3][128 * 32];   // 8 KB each
  __shared__ __align__(16) bf16 Bs[3][128 * 32];
  int tid = threadIdx.x;
  int lane = tid & 63;
  int wave = tid >> 6;
  int quad = lane >> 4, l16 = lane & 15;
  int wm = wave & 1, wn = wave >> 1;
  int row0 = blockIdx.x * 128;
  int col0 = blockIdx.y * 128;

  f32x4 acc[4][4] = {};

#define STAGE_QKV(buf, kb)                                                    \
  {                                                                           \
    _Pragma("unroll")                                                         \
    for (int j = 0; j < 2; ++j) {                                             \
      int slot = tid + 256 * j;                                               \
      int r = slot >> 2, s = slot & 3;                                        \
      int p = s ^ ((r >> 1) & 3);                                             \
      gl_lds16(Xb + (size_t)(row0 + r) * 256 + (kb) + p * 8,                  \
               (char*)As[buf] + slot * 16);                                   \
      gl_lds16(Wt + (size_t)(col0 + r) * CIN + (kb) + p * 8,                  \
               (char*)Bs[buf] + slot * 16);                                   \
    }                                                                         \
  }

  STAGE_QKV(0, 0);
  STAGE_QKV(1, 32);
  STAGE_QKV(2, 64);
#pragma unroll
  for (int t = 0; t < 8; ++t) {
    int cur = t % 3;
    if (t <= 5)      { asm volatile("s_waitcnt vmcnt(8)" ::: "memory"); }
    else if (t == 6) { asm volatile("s_waitcnt vmcnt(4)" ::: "memory"); }
    else             { asm volatile("s_waitcnt vmcnt(0)" ::: "memory"); }
    __builtin_amdgcn_sched_barrier(0);
    __builtin_amdgcn_s_barrier();                  // buf[cur] ready for all
    bf8_t afr[4], bfr[4];
#pragma unroll
    for (int mi = 0; mi < 4; ++mi) {
      int r = wm * 64 + mi * 16 + l16;
      int sA = quad ^ ((r >> 1) & 3);
      afr[mi] = *reinterpret_cast<const bf8_t*>(&As[cur][r * 32 + sA * 8]);
    }
#pragma unroll
    for (int ni = 0; ni < 4; ++ni) {
      int c = wn * 64 + ni * 16 + l16;
      int sB = quad ^ ((c >> 1) & 3);
      bfr[ni] = *reinterpret_cast<const bf8_t*>(&Bs[cur][c * 32 + sB * 8]);
    }
#pragma unroll
    for (int ni = 0; ni < 4; ++ni)
#pragma unroll
      for (int mi = 0; mi < 4; ++mi)
        acc[mi][ni] = MFMA16(afr[mi], bfr[ni], acc[mi][ni]);
    __builtin_amdgcn_s_barrier();                  // all done reading buf[cur]
    if (t < 5) STAGE_QKV(cur, (t + 3) * 32);       // overwrite for t+3
  }
#pragma unroll
  for (int mi = 0; mi < 4; ++mi)
#pragma unroll
    for (int ni = 0; ni < 4; ++ni)
#pragma unroll
      for (int rr = 0; rr < 4; ++rr) {
        int row = row0 + wm * 64 + mi * 16 + quad * 4 + rr;
        int col = col0 + wn * 64 + ni * 16 + l16;
        Y[(size_t)row * CQKV + col] = __float2bfloat16(acc[mi][ni][rr]);
      }
  // fused per-channel stats: sharded atomics (32 banks by blockIdx.x)
  int shard = (blockIdx.x & (NSH - 1)) * 1024;
#pragma unroll
  for (int ni = 0; ni < 4; ++ni) {
    float sp = 0.f, qp = 0.f;
#pragma unroll
    for (int mi = 0; mi < 4; ++mi)
#pragma unroll
      for (int rr = 0; rr < 4; ++rr) {
        float v = acc[mi][ni][rr];
        sp += v; qp += v * v;
      }
    sp += __shfl_xor(sp, 16); sp += __shfl_xor(sp, 32);
    qp += __shfl_xor(qp, 16); qp += __shfl_xor(qp, 32);
    if (quad == 0) {
      int c = col0 + wn * 64 + ni * 16 + l16;
      atomicAdd(&st[shard + c], sp);
      atomicAdd(&st[shard + CQKV + c], qp);
    }
  }
}

// ------------------- out GEMM (fp32 out), depth-3, sharded stats -----------
__global__ __launch_bounds__(256) void k_gemm_o(
    const bf16* __restrict__ AO, const bf16* __restrict__ Wto,
    float* __restrict__ Yo, float* __restrict__ st)
{
  __shared__ __align__(16) bf16 As[3][128 * 32];
  __shared__ __align__(16) bf16 Bs[3][128 * 32];
  int tid = threadIdx.x;
  int lane = tid & 63;
  int wave = tid >> 6;
  int quad = lane >> 4, l16 = lane & 15;
  int wm = wave & 1, wn = wave >> 1;
  int row0 = blockIdx.x * 128;

  f32x4 acc[4][4] = {};

#define STAGE_O(buf, kb)                                                      \
  {                                                                           \
    _Pragma("unroll")                                                         \
    for (int j = 0; j < 2; ++j) {                                             \
      int slot = tid + 256 * j;                                               \
      int r = slot >> 2, s = slot & 3;                                        \
      int p = s ^ ((r >> 1) & 3);                                             \
      gl_lds16(AO + (size_t)(row0 + r) * 128 + (kb) + p * 8,                  \
               (char*)As[buf] + slot * 16);                                   \
      gl_lds16(Wto + (size_t)r * 128 + (kb) + p * 8,                          \
               (char*)Bs[buf] + slot * 16);                                   \
    }                                                                         \
  }

  STAGE_O(0, 0);
  STAGE_O(1, 32);
  STAGE_O(2, 64);
#pragma unroll
  for (int t = 0; t < 4; ++t) {
    int cur = t % 3;
    if (t <= 1)      { asm volatile("s_waitcnt vmcnt(8)" ::: "memory"); }
    else if (t == 2) { asm volatile("s_waitcnt vmcnt(4)" ::: "memory"); }
    else             { asm volatile("s_waitcnt vmcnt(0)" ::: "memory"); }
    __builtin_amdgcn_sched_barrier(0);
    __builtin_amdgcn_s_barrier();
    bf8_t afr[4], bfr[4];
#pragma unroll
    for (int mi = 0; mi < 4; ++mi) {
      int r = wm * 64 + mi * 16 + l16;
      int sA = quad ^ ((r >> 1) & 3);
      afr[mi] = *reinterpret_cast<const bf8_t*>(&As[cur][r * 32 + sA * 8]);
    }
#pragma unroll
    for (int ni = 0; ni < 4; ++ni) {
      int c = wn * 64 + ni * 16 + l16;
      int sB = quad ^ ((c >> 1) & 3);
      bfr[ni] = *reinterpret_cast<const bf8_t*>(&Bs[cur][c * 32 + sB * 8]);
    }
#pragma unroll
    for (int ni = 0; ni < 4; ++ni)
#pragma unroll
      for (int mi = 0; mi < 4; ++mi)
        acc[mi][ni] = MFMA16(afr[mi], bfr[ni], acc[mi][ni]);
    __builtin_amdgcn_s_barrier();
    if (t < 1) STAGE_O(cur, (t + 3) * 32);
  }
#pragma unroll
  for (int mi = 0; mi < 4; ++mi)
#pragma unroll
    for (int ni = 0; ni < 4; ++ni)
#pragma unroll
      for (int rr = 0; rr < 4; ++rr) {
        int row = row0 + wm * 64 + mi * 16 + quad * 4 + rr;
        int col = wn * 64 + ni * 16 + l16;
        Yo[(size_t)row * 128 + col] = acc[mi][ni][rr];
      }
  int shard = (blockIdx.x & (NSH - 1)) * 1024;
#pragma unroll
  for (int ni = 0; ni < 4; ++ni) {
    float sp = 0.f, qp = 0.f;
#pragma unroll
    for (int mi = 0; mi < 4; ++mi)
#pragma unroll
      for (int rr = 0; rr < 4; ++rr) {
        float v = acc[mi][ni][rr];
        sp += v; qp += v * v;
      }
    sp += __shfl_xor(sp, 16); sp += __shfl_xor(sp, 32);
    qp += __shfl_xor(qp, 16); qp += __shfl_xor(qp, 32);
    if (quad == 0) {
      int c = wn * 64 + ni * 16 + l16;
      atomicAdd(&st[shard + 768 + c], sp);
      atomicAdd(&st[shard + 896 + c], qp);
    }
  }
}

// ------------------- norm+ReLU: K rows + V (chunk-major A-layout) ----------
// grid (384, 8). BN scales from 32-shard sums (threads 0..63).
__global__ __launch_bounds__(256) void k_norm_kv(
    const bf16* __restrict__ Y, const float* __restrict__ st,
    const float* __restrict__ gk, const float* __restrict__ bek,
    const float* __restrict__ gv, const float* __restrict__ bev,
    bf16* __restrict__ Kh, bf16* __restrict__ Vt)
{
  __shared__ short vs[64][40];
  __shared__ float scn[2][32], shn[2][32];
  int t = threadIdx.x;
  int bh = blockIdx.x, nc = blockIdx.y;
  int bt = bh >> 2, h = bh & 3;
  int n0 = nc * 64;
  int r = t >> 2, cg = t & 3;
  if (t < 64) {                        // per-block BN scales (K: kv=0, V: kv=1)
    int kv = t >> 5, i = t & 31;
    int c = 128 + kv * 128 + h * 32 + i;
    const float* g  = kv ? gv : gk;
    const float* be = kv ? bev : bek;
    float ssum = 0.f, qsum = 0.f;
#pragma unroll
    for (int sh = 0; sh < NSH; ++sh) {
      ssum += st[sh * 1024 + c];
      qsum += st[sh * 1024 + CQKV + c];
    }
    const float invr = 1.0f / (float)RR;
    float mu  = ssum * invr;
    float var = qsum * invr - mu * mu;
    float s = g[h * 32 + i] * rsqrtf(var + EPSB);
    scn[kv][i] = s;
    shn[kv][i] = be[h * 32 + i] - mu * s;
  }
  __syncthreads();
  // ---- K phase
  {
    int c = 128 + h * 32 + cg * 8;
    bf8_t y8 = *reinterpret_cast<const bf8_t*>(
        Y + ((size_t)bt * NN + n0 + r) * CQKV + c);
    bf8_t o8;
#pragma unroll
    for (int i = 0; i < 8; ++i)
      o8[i] = f2b(fmaxf(0.f, fmaf(b2f(y8[i]), scn[0][cg * 8 + i], shn[0][cg * 8 + i])));
    *reinterpret_cast<bf8_t*>(Kh + ((size_t)bh * NN + n0 + r) * 32 + cg * 8) = o8;
  }
  // ---- V phase (LDS transpose into permuted chunk-major A-layout)
  {
    int c = 256 + h * 32 + cg * 8;
    bf8_t y8 = *reinterpret_cast<const bf8_t*>(
        Y + ((size_t)bt * NN + n0 + r) * CQKV + c);
    bf8_t o8;
#pragma unroll
    for (int i = 0; i < 8; ++i)
      o8[i] = f2b(fmaxf(0.f, fmaf(b2f(y8[i]), scn[1][cg * 8 + i], shn[1][cg * 8 + i])));
    *reinterpret_cast<bf8_t*>(&vs[r][cg * 8]) = o8;
  }
  __syncthreads();
  int dim = t >> 3, kcl = (t >> 2) & 1, quad = t & 3;
  bf8_t w8;
#pragma unroll
  for (int j = 0; j < 8; ++j)
    w8[j] = vs[kcl * 32 + (j >> 2) * 16 + quad * 4 + (j & 3)][dim];
  *reinterpret_cast<bf8_t*>(Vt + (size_t)bh * 16384 +
                            (size_t)(nc * 2 + kcl) * 1024 + dim * 32 + quad * 8) = w8;
}

// ------------------- fused masked attention (grid 768, VALU diet) ----------
// grid 768: bh = x % 384 (XCD-local), halfq = x / 384; 4 q-tiles per wave.
// S^T = MFMA(K, Q): lane owns query l16. Max-free softmax (scores >= 0,
// folded base-2 exponent bounded ~30). Masking: P-fragment AND with bf16
// wordmasks Mx (L2-resident, shared by all bh). Denominator on the MFMA
// pipe: lacc = MFMA(ones, P, lacc) -> lane-local, no shuffles.
// NOTE: plain launch_bounds — (256,4) made the allocator spill (R10/R11).
__global__ __launch_bounds__(256) void k_attn(
    const bf16* __restrict__ Y, const float* __restrict__ st,
    const float* __restrict__ gq, const float* __restrict__ beq,
    const bf16* __restrict__ Kh, const bf16* __restrict__ Vt,
    const short* __restrict__ Mx, bf16* __restrict__ AO)
{
  __shared__ __align__(16) bf16 KbS[512 * 32];     // 32 KB, rows 64B swizzled
  __shared__ float sq[32], hq[32];
  int tid = threadIdx.x;
  int wave = tid >> 6, lane = tid & 63;
  int quad = lane >> 4, l16 = lane & 15;
  int bh = blockIdx.x % 384;
  int halfq = blockIdx.x / 384;                    // q-tile half (0/1)
  int bt = bh >> 2, h = bh & 3;
  const char* Kp = (const char*)(Kh + (size_t)bh * NN * 32);
  const bf16* Vp = Vt + (size_t)bh * NN * 32;

  // ---- stage K with row-chunk swizzle (DMA to KbS; scales overlap below)
#pragma unroll
  for (int i = 0; i < 8; ++i) {
    int t2 = wave * 8 + i;
    int r = t2 * 16 + (lane >> 2);
    int p = (lane & 3) ^ ((r >> 1) & 3);
    gl_lds16(Kp + (size_t)r * 64 + p * 16, (char*)KbS + t2 * 1024 + lane * 16);
  }
  if (tid < 32) {                      // q-channel BN scales, K2E folded
    int c = h * 32 + tid;
    float ssum = 0.f, qsum = 0.f;
#pragma unroll
    for (int sh = 0; sh < NSH; ++sh) {
      ssum += st[sh * 1024 + c];
      qsum += st[sh * 1024 + CQKV + c];
    }
    const float invr = 1.0f / (float)RR;
    float mu  = ssum * invr;
    float var = qsum * invr - mu * mu;
    float sc = gq[c] * rsqrtf(var + EPSB);
    sq[tid] = sc * K2E;
    hq[tid] = (beq[c] - mu * sc) * K2E;
  }
  __syncthreads();
  float scq[8], shq[8];
#pragma unroll
  for (int j = 0; j < 8; ++j) {
    scq[j] = sq[quad * 8 + j];
    shq[j] = hq[quad * 8 + j];
  }
  const short oneb = f2b(1.0f);
  const bf8_t ones = bf8_t{ oneb, oneb, oneb, oneb, oneb, oneb, oneb, oneb };

  const f32x4 zero = {0.f, 0.f, 0.f, 0.f};
#pragma unroll 1
  for (int it = 0; it < 4; ++it) {
    int nt = halfq * 16 + it * 4 + wave;           // global ntile 0..31
    int n0 = nt * 16;
    // Q inline norm+ReLU from Y: B-fragment (col=query l16, k=dim quad*8+j)
    int cq = h * 32 + quad * 8;
    bf8_t yq = *reinterpret_cast<const bf8_t*>(
        Y + ((size_t)bt * NN + n0 + l16) * CQKV + cq);
    bf8_t qf;
#pragma unroll
    for (int j = 0; j < 8; ++j)
      qf[j] = f2b(fmaxf(0.f, fmaf(b2f(yq[j]), scq[j], shq[j])));

    f32x4 o0 = zero, o1 = zero;                    // O^T dims 0-15 / 16-31
    f32x4 lacc = zero;                             // P row-sums via MFMA
    const short* Mbase = Mx + ((size_t)nt * 8 * 64 + lane) * 16;

#pragma unroll 2
    for (int c = 0; c < 8; ++c) {
      // S^T chunk: 4 tiles x 16 keys; lane = (key quad*4+rr, query l16)
      f32x4 s[4];
#pragma unroll
      for (int mt = 0; mt < 4; ++mt) {
        int r = (c * 4 + mt) * 16 + l16;
        bf8_t kf = *reinterpret_cast<const bf8_t*>(
            (const char*)KbS + (size_t)r * 64 + ((quad ^ ((r >> 1) & 3)) * 16));
        s[mt] = MFMA16(kf, qf, zero);
      }
      // wordmasks for this chunk (32 B/lane, coalesced 2 KB/wave, L2-hot)
      const short* mrow = Mbase + (size_t)c * 64 * 16;
      bf8_t m0 = *reinterpret_cast<const bf8_t*>(mrow);
      bf8_t m1 = *reinterpret_cast<const bf8_t*>(mrow + 8);
      // exp2 (unconditional) + pack; mask via bitwise AND
      bf8_t f0, f1;
#pragma unroll
      for (int mt = 0; mt < 2; ++mt)
#pragma unroll
        for (int rr = 0; rr < 4; ++rr)
          f0[mt * 4 + rr] = f2b(fexp2(s[mt][rr]));
#pragma unroll
      for (int mt = 2; mt < 4; ++mt)
#pragma unroll
        for (int rr = 0; rr < 4; ++rr)
          f1[(mt - 2) * 4 + rr] = f2b(fexp2(s[mt][rr]));
      f0 &= m0;
      f1 &= m1;
      // denominator on the MFMA pipe: rows of C all equal sum_k P[k][query]
      lacc = MFMA16(ones, f0, lacc);
      lacc = MFMA16(ones, f1, lacc);
      // PV: O^T += V^T_chunk . P^T_chunk  (Vt chunk-major, coalesced 1 KB)
      const bf16* va = Vp + (size_t)c * 2048 + l16 * 32 + quad * 8;
      o0 = MFMA16(*reinterpret_cast<const bf8_t*>(va),        f0, o0);
      o0 = MFMA16(*reinterpret_cast<const bf8_t*>(va + 1024), f1, o0);
      o1 = MFMA16(*reinterpret_cast<const bf8_t*>(va + 512),  f0, o1);
      o1 = MFMA16(*reinterpret_cast<const bf8_t*>(va + 1536), f1, o1);
    }
    // final: lacc[0] = full P-row sum for query l16 (lane-local, no shuffle)
    float inv = 1.0f / lacc[0];
    unsigned int w0 = pk2(o0[0] * inv, o0[1] * inv);   // dims q*4+0, +1
    unsigned int w1 = pk2(o0[2] * inv, o0[3] * inv);   // dims q*4+2, +3
    unsigned int w2 = pk2(o1[0] * inv, o1[1] * inv);   // dims 16+q*4+0, +1
    unsigned int w3 = pk2(o1[2] * inv, o1[3] * inv);
    // butterfly: lane(quad,l16) gathers dims quad*8..+7 of its query l16
    int sL0 = (quad & 1) * 32 + l16;
    int sL1 = sL0 + 16;
    bool hi = quad >= 2;
    unsigned int a0 = __shfl(w0, sL0), b0 = __shfl(w2, sL0);
    unsigned int a1 = __shfl(w1, sL0), b1 = __shfl(w3, sL0);
    unsigned int a2 = __shfl(w0, sL1), b2 = __shfl(w2, sL1);
    unsigned int a3 = __shfl(w1, sL1), b3 = __shfl(w3, sL1);
    u32x4 ov = { hi ? b0 : a0, hi ? b1 : a1, hi ? b2 : a2, hi ? b3 : a3 };
    *reinterpret_cast<u32x4*>(
        AO + ((size_t)bt * NN + n0 + l16) * DD + h * 32 + quad * 8) = ov;
  }
}

// ------------------- final BN + ReLU (scales once per block via LDS) -------
__global__ __launch_bounds__(256) void k_norm_o(
    const float* __restrict__ Yo, const float* __restrict__ st,
    const float* __restrict__ g, const float* __restrict__ be,
    float* __restrict__ out)
{
  __shared__ float scs[128], shs[128];
  int t = threadIdx.x;
  if (t < 128) {
    float ssum = 0.f, qsum = 0.f;
#pragma unroll
    for (int sh = 0; sh < NSH; ++sh) {
      ssum += st[sh * 1024 + 768 + t];
      qsum += st[sh * 1024 + 896 + t];
    }
    const float inv = 1.0f / (float)RR;
    float mu  = ssum * inv;
    float var = qsum * inv - mu * mu;
    float sc = g[t] * rsqrtf(var + EPSB);
    scs[t] = sc;
    shs[t] = be[t] - mu * sc;
  }
  __syncthreads();
  int idx = blockIdx.x * 256 + t;                // < RR*128
  int c = idx & 127;
  out[idx] = fmaxf(0.f, fmaf(Yo[idx], scs[c], shs[c]));
}

// ---------------------------------------------------------------------------
extern "C" void kernel_launch(void* const* d_in, const int* in_sizes, int n_in,
                              void* d_out, int out_size, void* d_ws, size_t ws_size,
                              hipStream_t stream)
{
  const float* X    = (const float*)d_in[0];
  const float* STE  = (const float*)d_in[1];
  const float* Am   = (const float*)d_in[2];
  const float* Wq   = (const float*)d_in[3];
  const float* gq   = (const float*)d_in[5];
  const float* beq  = (const float*)d_in[6];
  const float* Wk   = (const float*)d_in[7];
  const float* gk   = (const float*)d_in[9];
  const float* bek  = (const float*)d_in[10];
  const float* Wv   = (const float*)d_in[11];
  const float* gv   = (const float*)d_in[13];
  const float* bev  = (const float*)d_in[14];
  const float* Wo   = (const float*)d_in[15];
  const float* go   = (const float*)d_in[17];
  const float* beo  = (const float*)d_in[18];
  // biases d_in[4,8,12,16] unused: BN subtracts batch mean -> bias cancels.

  char* ws = (char*)d_ws;
  bf16*  Yqkv = (bf16*)(ws + 0);            // 37,748,736
  float* Yo   = (float*)(ws + 0);           // aliases Yqkv (dead after attn)
  bf16*  Xb   = (bf16*)(ws + 50331648);     // 25,165,824 — aliases Kh/Vt:
                                            //   dead before k_norm_kv runs
  bf16*  Kh   = (bf16*)(ws + 50331648);
  bf16*  Vt   = (bf16*)(ws + 62914560);
  bf16*  AO   = (bf16*)(ws + 75497472);
  bf16*  Wtq  = (bf16*)(ws + 88080384);     // 196,608
  bf16*  Wto  = (bf16*)(ws + 88276992);     // 32,768
  short* Mx   = (short*)(ws + 88309760);    // 524,288 wordmasks
  float* st   = (float*)(ws + 88834048);    // 32 shards x 1024 floats (128KB)

  k_prep<<<6784, 256, 0, stream>>>(Wq, Wk, Wv, Wo, Am, X, STE,
                                   Wtq, Wto, Mx, st, Xb);
  k_gemm_qkv<<<dim3(RR / 128, 3), 256, 0, stream>>>(Xb, Wtq, Yqkv, st);
  k_norm_kv<<<dim3(CQKV, 8), 256, 0, stream>>>(Yqkv, st, gk, bek, gv, bev,
                                               Kh, Vt);
  k_attn<<<768, 256, 0, stream>>>(Yqkv, st, gq, beq, Kh, Vt, Mx, AO);
  k_gemm_o<<<RR / 128, 256, 0, stream>>>(AO, Wto, Yo, st);
  k_norm_o<<<(RR * 128) / 256, 256, 0, stream>>>(Yo, st, go, beo, (float*)d_out);
}

// Round 15
// 217.324 us; speedup vs baseline: 1.1387x; 1.1387x over previous
//
#include <hip/hip_runtime.h>
#include <hip/hip_bf16.h>

// ---------------------------------------------------------------------------
// SpatialAttention — ROUND 24 (= R22 exactly + dual-q-tile interleaved attn).
//  * R23 post-mortem: VALU diet twice-confirmed mechanically (VALU 46->36.7)
//    and twice dur-flat -> k_attn is LATENCY-CHAIN bound, not VALU bound;
//    R23's Mx/32-shard extras cost +15us elsewhere. Full revert to R22 base
//    (NSH=8, Amb bitmask, scalar lrun).
//  * k_attn: process TWO independent q-tiles (nt, nt+4) per chunk-loop pass:
//    doubled ILP on the same wave (two independent S->exp->PV chains for the
//    scheduler to interleave), K LDS-fragment reads shared (LDS reads and
//    bank conflicts halve), V L2-loads shared (each feeds 4 MFMAs). VGPR was
//    52 -> plenty of headroom. Iteration loop 4 -> 2 passes.
//  * GEMMs / k_prep / k_norm_kv / k_norm_o / shards: identical to R22 (232us
//    measured best).
//  * R12 lesson kept: NO second __launch_bounds__ arg on k_attn.
// Sizes: BT=96, N=512, D=128, heads=4, hd=32, RR=49152. Biases cancel in BN.
// ---------------------------------------------------------------------------

#define BT   96
#define NN   512
#define DD   128
#define CIN  256
#define CQKV 384
#define RR   49152
#define EPSB 1e-5f
#define K2E  0.7213475204444817f   // 0.5 * log2(e)

using bf16  = __hip_bfloat16;
using bf8_t = __attribute__((ext_vector_type(8))) short;   // 8 x bf16
using f32x4 = __attribute__((ext_vector_type(4))) float;
using u32x4 = __attribute__((ext_vector_type(4))) unsigned int;

#define MFMA16(a,b,c) __builtin_amdgcn_mfma_f32_16x16x32_bf16((a),(b),(c),0,0,0)

__device__ __forceinline__ short f2b(float f) {
  bf16 h = __float2bfloat16(f);
  return *reinterpret_cast<short*>(&h);
}
__device__ __forceinline__ float b2f(short s) {
  bf16 h; *reinterpret_cast<short*>(&h) = s;
  return __bfloat162float(h);
}
__device__ __forceinline__ float fexp2(float x) {
#if __has_builtin(__builtin_amdgcn_exp2f)
  return __builtin_amdgcn_exp2f(x);
#else
  return exp2f(x);
#endif
}
__device__ __forceinline__ unsigned int pk2(float lo, float hi) {
  return (unsigned int)(unsigned short)f2b(lo) |
         ((unsigned int)(unsigned short)f2b(hi) << 16);
}
__device__ __forceinline__ void gl_lds16(const void* g, void* l) {
  __builtin_amdgcn_global_load_lds(
      (const __attribute__((address_space(1))) unsigned int*)g,
      (__attribute__((address_space(3))) unsigned int*)l, 16, 0, 0);
}

// ------------------- prep: W transpose + mask + zero stats + X||STE cvt ----
// Items: 98304 (Wtq) + 16384 (Wto) + 8192 (Amb) + 8192 (st shards) +
// 1572864 (cvt) = 1703936 -> grid 6656 x 256.
__global__ __launch_bounds__(256) void k_prep(
    const float* __restrict__ Wq, const float* __restrict__ Wk,
    const float* __restrict__ Wv, const float* __restrict__ Wo,
    const float* __restrict__ Am, const float* __restrict__ X,
    const float* __restrict__ STE,
    bf16* __restrict__ Wtq, bf16* __restrict__ Wto,
    unsigned int* __restrict__ Amb, float* __restrict__ st,
    bf16* __restrict__ Xb)
{
  int idx = blockIdx.x * 256 + threadIdx.x;
  if (idx < CQKV * CIN) {                          // Wtq[c][k] = W[k][c]
    int c = idx >> 8;
    int k = idx & 255;
    const float* W = (c < 128) ? Wq : ((c < 256) ? Wk : Wv);
    int cl = c & 127;
    Wtq[idx] = __float2bfloat16(W[(size_t)k * 128 + cl]);
  } else if (idx < CQKV * CIN + 128 * 128) {       // Wto[c][k] = Wo[k][c]
    int j = idx - CQKV * CIN;
    int c = j >> 7, k = j & 127;
    Wto[j] = __float2bfloat16(Wo[(size_t)k * 128 + c]);
  } else if (idx < CQKV * CIN + 128 * 128 + 8192) {  // Amb[n][l16] bit mt
    int j = idx - (CQKV * CIN + 128 * 128);
    int l16 = j & 15, n = j >> 4;
    unsigned int w = 0;
#pragma unroll
    for (int mt = 0; mt < 32; ++mt)
      if (Am[(size_t)n * NN + mt * 16 + l16] > 0.f) w |= (1u << mt);
    Amb[j] = w;
  } else if (idx < CQKV * CIN + 128 * 128 + 8192 + 8192) {  // 8 shard banks
    st[idx - (CQKV * CIN + 128 * 128 + 8192)] = 0.f;
  } else {                                         // X||STE -> bf16 Xb
    int j = idx - (CQKV * CIN + 128 * 128 + 8192 + 8192);
    int row = j >> 5, cg = j & 31;                 // 8 cols per thread
    const float* src = (cg < 16) ? (X + (size_t)row * 128 + cg * 8)
                                 : (STE + (size_t)row * 128 + (cg - 16) * 8);
    f32x4 a = *reinterpret_cast<const f32x4*>(src);
    f32x4 b = *reinterpret_cast<const f32x4*>(src + 4);
    bf8_t o = bf8_t{ f2b(a[0]), f2b(a[1]), f2b(a[2]), f2b(a[3]),
                     f2b(b[0]), f2b(b[1]), f2b(b[2]), f2b(b[3]) };
    *reinterpret_cast<bf8_t*>(Xb + (size_t)row * 256 + cg * 8) = o;
  }
}

// ------------------- QKV GEMM + fused stats (depth-3 vmcnt pipeline) -------
// grid (384,3); 128x128 tile, BK=32, 8 k-steps, 3 LDS buffers (48 KB).
// Stats atomics sharded 8-ways by blockIdx.x to break L2 address chains.
__global__ __launch_bounds__(256) void k_gemm_qkv(
    const bf16* __restrict__ Xb, const bf16* __restrict__ Wt,
    bf16* __restrict__ Y, float* __restrict__ st)
{
  __shared__ __align__(16) bf16 As[3][128 * 32];   // 8 KB each
  __shared__ __align__(16) bf16 Bs[3][128 * 32];
  int tid = threadIdx.x;
  int lane = tid & 63;
  int wave = tid >> 6;
  int quad = lane >> 4, l16 = lane & 15;
  int wm = wave & 1, wn = wave >> 1;
  int row0 = blockIdx.x * 128;
  int col0 = blockIdx.y * 128;

  f32x4 acc[4][4] = {};

#define STAGE_QKV(buf, kb)                                                    \
  {                                                                           \
    _Pragma("unroll")                                                         \
    for (int j = 0; j < 2; ++j) {                                             \
      int slot = tid + 256 * j;                                               \
      int r = slot >> 2, s = slot & 3;                                        \
      int p = s ^ ((r >> 1) & 3);                                             \
      gl_lds16(Xb + (size_t)(row0 + r) * 256 + (kb) + p * 8,                  \
               (char*)As[buf] + slot * 16);                                   \
      gl_lds16(Wt + (size_t)(col0 + r) * CIN + (kb) + p * 8,                  \
               (char*)Bs[buf] + slot * 16);                                   \
    }                                                                         \
  }

  STAGE_QKV(0, 0);
  STAGE_QKV(1, 32);
  STAGE_QKV(2, 64);
#pragma unroll
  for (int t = 0; t < 8; ++t) {
    int cur = t % 3;
    if (t <= 5)      { asm volatile("s_waitcnt vmcnt(8)" ::: "memory"); }
    else if (t == 6) { asm volatile("s_waitcnt vmcnt(4)" ::: "memory"); }
    else             { asm volatile("s_waitcnt vmcnt(0)" ::: "memory"); }
    __builtin_amdgcn_sched_barrier(0);
    __builtin_amdgcn_s_barrier();                  // buf[cur] ready for all
    bf8_t afr[4], bfr[4];
#pragma unroll
    for (int mi = 0; mi < 4; ++mi) {
      int r = wm * 64 + mi * 16 + l16;
      int sA = quad ^ ((r >> 1) & 3);
      afr[mi] = *reinterpret_cast<const bf8_t*>(&As[cur][r * 32 + sA * 8]);
    }
#pragma unroll
    for (int ni = 0; ni < 4; ++ni) {
      int c = wn * 64 + ni * 16 + l16;
      int sB = quad ^ ((c >> 1) & 3);
      bfr[ni] = *reinterpret_cast<const bf8_t*>(&Bs[cur][c * 32 + sB * 8]);
    }
#pragma unroll
    for (int ni = 0; ni < 4; ++ni)
#pragma unroll
      for (int mi = 0; mi < 4; ++mi)
        acc[mi][ni] = MFMA16(afr[mi], bfr[ni], acc[mi][ni]);
    __builtin_amdgcn_s_barrier();                  // all done reading buf[cur]
    if (t < 5) STAGE_QKV(cur, (t + 3) * 32);       // overwrite for t+3
  }
#pragma unroll
  for (int mi = 0; mi < 4; ++mi)
#pragma unroll
    for (int ni = 0; ni < 4; ++ni)
#pragma unroll
      for (int rr = 0; rr < 4; ++rr) {
        int row = row0 + wm * 64 + mi * 16 + quad * 4 + rr;
        int col = col0 + wn * 64 + ni * 16 + l16;
        Y[(size_t)row * CQKV + col] = __float2bfloat16(acc[mi][ni][rr]);
      }
  // fused per-channel stats: sharded atomics (8 banks by blockIdx.x)
  int shard = (blockIdx.x & 7) * 1024;
#pragma unroll
  for (int ni = 0; ni < 4; ++ni) {
    float sp = 0.f, qp = 0.f;
#pragma unroll
    for (int mi = 0; mi < 4; ++mi)
#pragma unroll
      for (int rr = 0; rr < 4; ++rr) {
        float v = acc[mi][ni][rr];
        sp += v; qp += v * v;
      }
    sp += __shfl_xor(sp, 16); sp += __shfl_xor(sp, 32);
    qp += __shfl_xor(qp, 16); qp += __shfl_xor(qp, 32);
    if (quad == 0) {
      int c = col0 + wn * 64 + ni * 16 + l16;
      atomicAdd(&st[shard + c], sp);
      atomicAdd(&st[shard + CQKV + c], qp);
    }
  }
}

// ------------------- out GEMM (fp32 out), depth-3, sharded stats -----------
__global__ __launch_bounds__(256) void k_gemm_o(
    const bf16* __restrict__ AO, const bf16* __restrict__ Wto,
    float* __restrict__ Yo, float* __restrict__ st)
{
  __shared__ __align__(16) bf16 As[3][128 * 32];
  __shared__ __align__(16) bf16 Bs[3][128 * 32];
  int tid = threadIdx.x;
  int lane = tid & 63;
  int wave = tid >> 6;
  int quad = lane >> 4, l16 = lane & 15;
  int wm = wave & 1, wn = wave >> 1;
  int row0 = blockIdx.x * 128;

  f32x4 acc[4][4] = {};

#define STAGE_O(buf, kb)                                                      \
  {                                                                           \
    _Pragma("unroll")                                                         \
    for (int j = 0; j < 2; ++j) {                                             \
      int slot = tid + 256 * j;                                               \
      int r = slot >> 2, s = slot & 3;                                        \
      int p = s ^ ((r >> 1) & 3);                                             \
      gl_lds16(AO + (size_t)(row0 + r) * 128 + (kb) + p * 8,                  \
               (char*)As[buf] + slot * 16);                                   \
      gl_lds16(Wto + (size_t)r * 128 + (kb) + p * 8,                          \
               (char*)Bs[buf] + slot * 16);                                   \
    }                                                                         \
  }

  STAGE_O(0, 0);
  STAGE_O(1, 32);
  STAGE_O(2, 64);
#pragma unroll
  for (int t = 0; t < 4; ++t) {
    int cur = t % 3;
    if (t <= 1)      { asm volatile("s_waitcnt vmcnt(8)" ::: "memory"); }
    else if (t == 2) { asm volatile("s_waitcnt vmcnt(4)" ::: "memory"); }
    else             { asm volatile("s_waitcnt vmcnt(0)" ::: "memory"); }
    __builtin_amdgcn_sched_barrier(0);
    __builtin_amdgcn_s_barrier();
    bf8_t afr[4], bfr[4];
#pragma unroll
    for (int mi = 0; mi < 4; ++mi) {
      int r = wm * 64 + mi * 16 + l16;
      int sA = quad ^ ((r >> 1) & 3);
      afr[mi] = *reinterpret_cast<const bf8_t*>(&As[cur][r * 32 + sA * 8]);
    }
#pragma unroll
    for (int ni = 0; ni < 4; ++ni) {
      int c = wn * 64 + ni * 16 + l16;
      int sB = quad ^ ((c >> 1) & 3);
      bfr[ni] = *reinterpret_cast<const bf8_t*>(&Bs[cur][c * 32 + sB * 8]);
    }
#pragma unroll
    for (int ni = 0; ni < 4; ++ni)
#pragma unroll
      for (int mi = 0; mi < 4; ++mi)
        acc[mi][ni] = MFMA16(afr[mi], bfr[ni], acc[mi][ni]);
    __builtin_amdgcn_s_barrier();
    if (t < 1) STAGE_O(cur, (t + 3) * 32);
  }
#pragma unroll
  for (int mi = 0; mi < 4; ++mi)
#pragma unroll
    for (int ni = 0; ni < 4; ++ni)
#pragma unroll
      for (int rr = 0; rr < 4; ++rr) {
        int row = row0 + wm * 64 + mi * 16 + quad * 4 + rr;
        int col = wn * 64 + ni * 16 + l16;
        Yo[(size_t)row * 128 + col] = acc[mi][ni][rr];
      }
  int shard = (blockIdx.x & 7) * 1024;
#pragma unroll
  for (int ni = 0; ni < 4; ++ni) {
    float sp = 0.f, qp = 0.f;
#pragma unroll
    for (int mi = 0; mi < 4; ++mi)
#pragma unroll
      for (int rr = 0; rr < 4; ++rr) {
        float v = acc[mi][ni][rr];
        sp += v; qp += v * v;
      }
    sp += __shfl_xor(sp, 16); sp += __shfl_xor(sp, 32);
    qp += __shfl_xor(qp, 16); qp += __shfl_xor(qp, 32);
    if (quad == 0) {
      int c = wn * 64 + ni * 16 + l16;
      atomicAdd(&st[shard + 768 + c], sp);
      atomicAdd(&st[shard + 896 + c], qp);
    }
  }
}

// ------------------- norm+ReLU: K rows + V (chunk-major A-layout) ----------
// grid (384, 8). BN scales from 8-shard sums (threads 0..63).
__global__ __launch_bounds__(256) void k_norm_kv(
    const bf16* __restrict__ Y, const float* __restrict__ st,
    const float* __restrict__ gk, const float* __restrict__ bek,
    const float* __restrict__ gv, const float* __restrict__ bev,
    bf16* __restrict__ Kh, bf16* __restrict__ Vt)
{
  __shared__ short vs[64][40];
  __shared__ float scn[2][32], shn[2][32];
  int t = threadIdx.x;
  int bh = blockIdx.x, nc = blockIdx.y;
  int bt = bh >> 2, h = bh & 3;
  int n0 = nc * 64;
  int r = t >> 2, cg = t & 3;
  if (t < 64) {                        // per-block BN scales (K: kv=0, V: kv=1)
    int kv = t >> 5, i = t & 31;
    int c = 128 + kv * 128 + h * 32 + i;
    const float* g  = kv ? gv : gk;
    const float* be = kv ? bev : bek;
    float ssum = 0.f, qsum = 0.f;
#pragma unroll
    for (int sh = 0; sh < 8; ++sh) {
      ssum += st[sh * 1024 + c];
      qsum += st[sh * 1024 + CQKV + c];
    }
    const float invr = 1.0f / (float)RR;
    float mu  = ssum * invr;
    float var = qsum * invr - mu * mu;
    float s = g[h * 32 + i] * rsqrtf(var + EPSB);
    scn[kv][i] = s;
    shn[kv][i] = be[h * 32 + i] - mu * s;
  }
  __syncthreads();
  // ---- K phase
  {
    int c = 128 + h * 32 + cg * 8;
    bf8_t y8 = *reinterpret_cast<const bf8_t*>(
        Y + ((size_t)bt * NN + n0 + r) * CQKV + c);
    bf8_t o8;
#pragma unroll
    for (int i = 0; i < 8; ++i)
      o8[i] = f2b(fmaxf(0.f, fmaf(b2f(y8[i]), scn[0][cg * 8 + i], shn[0][cg * 8 + i])));
    *reinterpret_cast<bf8_t*>(Kh + ((size_t)bh * NN + n0 + r) * 32 + cg * 8) = o8;
  }
  // ---- V phase (LDS transpose into permuted chunk-major A-layout)
  {
    int c = 256 + h * 32 + cg * 8;
    bf8_t y8 = *reinterpret_cast<const bf8_t*>(
        Y + ((size_t)bt * NN + n0 + r) * CQKV + c);
    bf8_t o8;
#pragma unroll
    for (int i = 0; i < 8; ++i)
      o8[i] = f2b(fmaxf(0.f, fmaf(b2f(y8[i]), scn[1][cg * 8 + i], shn[1][cg * 8 + i])));
    *reinterpret_cast<bf8_t*>(&vs[r][cg * 8]) = o8;
  }
  __syncthreads();
  int dim = t >> 3, kcl = (t >> 2) & 1, quad = t & 3;
  bf8_t w8;
#pragma unroll
  for (int j = 0; j < 8; ++j)
    w8[j] = vs[kcl * 32 + (j >> 2) * 16 + quad * 4 + (j & 3)][dim];
  *reinterpret_cast<bf8_t*>(Vt + (size_t)bh * 16384 +
                            (size_t)(nc * 2 + kcl) * 1024 + dim * 32 + quad * 8) = w8;
}

// ------------------- fused masked attention (dual q-tile interleave) -------
// grid 768: bh = x % 384 (XCD-local), halfq = x / 384. Per pass each wave
// processes TWO independent q-tiles (nt0 = halfq*16+it*8+wave, nt1 = nt0+4):
// two independent S->exp2->PV chains give the scheduler ILP to fill latency;
// K LDS fragments and V L2 loads are shared between the tiles (each load
// feeds twice the MFMAs; LDS reads and bank conflicts halve).
// Max-free softmax (scores >= 0, folded base-2 exponent bounded ~30).
// NOTE: plain launch_bounds — (256,4) made the allocator spill (R10/R11).
__global__ __launch_bounds__(256) void k_attn(
    const bf16* __restrict__ Y, const float* __restrict__ st,
    const float* __restrict__ gq, const float* __restrict__ beq,
    const bf16* __restrict__ Kh, const bf16* __restrict__ Vt,
    const unsigned int* __restrict__ Amb, bf16* __restrict__ AO)
{
  __shared__ __align__(16) bf16 KbS[512 * 32];     // 32 KB, rows 64B swizzled
  __shared__ float sq[32], hq[32];
  int tid = threadIdx.x;
  int wave = tid >> 6, lane = tid & 63;
  int quad = lane >> 4, l16 = lane & 15;
  int bh = blockIdx.x % 384;
  int halfq = blockIdx.x / 384;                    // q-tile half (0/1)
  int bt = bh >> 2, h = bh & 3;
  const char* Kp = (const char*)(Kh + (size_t)bh * NN * 32);
  const bf16* Vp = Vt + (size_t)bh * NN * 32;

  // ---- stage K with row-chunk swizzle (DMA to KbS; scales overlap below)
#pragma unroll
  for (int i = 0; i < 8; ++i) {
    int t2 = wave * 8 + i;
    int r = t2 * 16 + (lane >> 2);
    int p = (lane & 3) ^ ((r >> 1) & 3);
    gl_lds16(Kp + (size_t)r * 64 + p * 16, (char*)KbS + t2 * 1024 + lane * 16);
  }
  if (tid < 32) {                      // q-channel BN scales, K2E folded
    int c = h * 32 + tid;
    float ssum = 0.f, qsum = 0.f;
#pragma unroll
    for (int sh = 0; sh < 8; ++sh) {
      ssum += st[sh * 1024 + c];
      qsum += st[sh * 1024 + CQKV + c];
    }
    const float invr = 1.0f / (float)RR;
    float mu  = ssum * invr;
    float var = qsum * invr - mu * mu;
    float sc = gq[c] * rsqrtf(var + EPSB);
    sq[tid] = sc * K2E;
    hq[tid] = (beq[c] - mu * sc) * K2E;
  }
  __syncthreads();
  float scq[8], shq[8];
#pragma unroll
  for (int j = 0; j < 8; ++j) {
    scq[j] = sq[quad * 8 + j];
    shq[j] = hq[quad * 8 + j];
  }

  const f32x4 zero = {0.f, 0.f, 0.f, 0.f};
#pragma unroll 1
  for (int it = 0; it < 2; ++it) {
    int nt0 = halfq * 16 + it * 8 + wave;          // q-tile A
    int nt1 = nt0 + 4;                             // q-tile B
    int n00 = nt0 * 16, n01 = nt1 * 16;
    int cq = h * 32 + quad * 8;
    // Q inline norm+ReLU for both tiles
    bf8_t yq0 = *reinterpret_cast<const bf8_t*>(
        Y + ((size_t)bt * NN + n00 + l16) * CQKV + cq);
    bf8_t yq1 = *reinterpret_cast<const bf8_t*>(
        Y + ((size_t)bt * NN + n01 + l16) * CQKV + cq);
    bf8_t qf0, qf1;
#pragma unroll
    for (int j = 0; j < 8; ++j) {
      qf0[j] = f2b(fmaxf(0.f, fmaf(b2f(yq0[j]), scq[j], shq[j])));
      qf1[j] = f2b(fmaxf(0.f, fmaf(b2f(yq1[j]), scq[j], shq[j])));
    }
    unsigned int wm0[4], wm1[4];
#pragma unroll
    for (int rr = 0; rr < 4; ++rr) {
      wm0[rr] = Amb[(size_t)(n00 + l16) * 16 + quad * 4 + rr];
      wm1[rr] = Amb[(size_t)(n01 + l16) * 16 + quad * 4 + rr];
    }

    f32x4 o00 = zero, o01 = zero;                  // tile A: dims 0-15/16-31
    f32x4 o10 = zero, o11 = zero;                  // tile B
    float lr0 = 0.f, lr1 = 0.f;

#pragma unroll 2
    for (int c = 0; c < 8; ++c) {
      // S^T chunks for both tiles; K fragment loaded once, used twice
      f32x4 s0[4], s1[4];
#pragma unroll
      for (int mt = 0; mt < 4; ++mt) {
        int r = (c * 4 + mt) * 16 + l16;
        bf8_t kf = *reinterpret_cast<const bf8_t*>(
            (const char*)KbS + (size_t)r * 64 + ((quad ^ ((r >> 1) & 3)) * 16));
        s0[mt] = MFMA16(kf, qf0, zero);
        s1[mt] = MFMA16(kf, qf1, zero);
      }
      // exp2 + mask->0 + partial sums + pack PV B-fragments (both tiles)
      bf8_t f00, f01, f10, f11;
#pragma unroll
      for (int mt = 0; mt < 2; ++mt)
#pragma unroll
        for (int rr = 0; rr < 4; ++rr) {
          float p0 = ((wm0[rr] >> (c * 4 + mt)) & 1u) ? fexp2(s0[mt][rr]) : 0.f;
          float p1 = ((wm1[rr] >> (c * 4 + mt)) & 1u) ? fexp2(s1[mt][rr]) : 0.f;
          lr0 += p0; lr1 += p1;
          f00[mt * 4 + rr] = f2b(p0);
          f10[mt * 4 + rr] = f2b(p1);
        }
#pragma unroll
      for (int mt = 2; mt < 4; ++mt)
#pragma unroll
        for (int rr = 0; rr < 4; ++rr) {
          float p0 = ((wm0[rr] >> (c * 4 + mt)) & 1u) ? fexp2(s0[mt][rr]) : 0.f;
          float p1 = ((wm1[rr] >> (c * 4 + mt)) & 1u) ? fexp2(s1[mt][rr]) : 0.f;
          lr0 += p0; lr1 += p1;
          f01[(mt - 2) * 4 + rr] = f2b(p0);
          f11[(mt - 2) * 4 + rr] = f2b(p1);
        }
      // PV: V fragments loaded once, each feeds both tiles (4 MFMAs/load)
      const bf16* va = Vp + (size_t)c * 2048 + l16 * 32 + quad * 8;
      bf8_t vb0 = *reinterpret_cast<const bf8_t*>(va);
      bf8_t vb1 = *reinterpret_cast<const bf8_t*>(va + 1024);
      bf8_t vb2 = *reinterpret_cast<const bf8_t*>(va + 512);
      bf8_t vb3 = *reinterpret_cast<const bf8_t*>(va + 1536);
      o00 = MFMA16(vb0, f00, o00);
      o10 = MFMA16(vb0, f10, o10);
      o00 = MFMA16(vb1, f01, o00);
      o10 = MFMA16(vb1, f11, o10);
      o01 = MFMA16(vb2, f00, o01);
      o11 = MFMA16(vb2, f10, o11);
      o01 = MFMA16(vb3, f01, o01);
      o11 = MFMA16(vb3, f11, o11);
    }
    // epilogue per tile: reduce l, divide, butterfly, store
#pragma unroll
    for (int tile = 0; tile < 2; ++tile) {
      float lrun = tile ? lr1 : lr0;
      f32x4 oa = tile ? o10 : o00;
      f32x4 ob = tile ? o11 : o01;
      int n0 = tile ? n01 : n00;
      lrun += __shfl_xor(lrun, 16);
      lrun += __shfl_xor(lrun, 32);
      float inv = 1.0f / lrun;
      unsigned int w0 = pk2(oa[0] * inv, oa[1] * inv);
      unsigned int w1 = pk2(oa[2] * inv, oa[3] * inv);
      unsigned int w2 = pk2(ob[0] * inv, ob[1] * inv);
      unsigned int w3 = pk2(ob[2] * inv, ob[3] * inv);
      int sL0 = (quad & 1) * 32 + l16;
      int sL1 = sL0 + 16;
      bool hi = quad >= 2;
      unsigned int a0 = __shfl(w0, sL0), b0 = __shfl(w2, sL0);
      unsigned int a1 = __shfl(w1, sL0), b1 = __shfl(w3, sL0);
      unsigned int a2 = __shfl(w0, sL1), b2 = __shfl(w2, sL1);
      unsigned int a3 = __shfl(w1, sL1), b3 = __shfl(w3, sL1);
      u32x4 ov = { hi ? b0 : a0, hi ? b1 : a1, hi ? b2 : a2, hi ? b3 : a3 };
      *reinterpret_cast<u32x4*>(
          AO + ((size_t)bt * NN + n0 + l16) * DD + h * 32 + quad * 8) = ov;
    }
  }
}

// ------------------- final BN + ReLU (scales once per block via LDS) -------
__global__ __launch_bounds__(256) void k_norm_o(
    const float* __restrict__ Yo, const float* __restrict__ st,
    const float* __restrict__ g, const float* __restrict__ be,
    float* __restrict__ out)
{
  __shared__ float scs[128], shs[128];
  int t = threadIdx.x;
  if (t < 128) {
    float ssum = 0.f, qsum = 0.f;
#pragma unroll
    for (int sh = 0; sh < 8; ++sh) {
      ssum += st[sh * 1024 + 768 + t];
      qsum += st[sh * 1024 + 896 + t];
    }
    const float inv = 1.0f / (float)RR;
    float mu  = ssum * inv;
    float var = qsum * inv - mu * mu;
    float sc = g[t] * rsqrtf(var + EPSB);
    scs[t] = sc;
    shs[t] = be[t] - mu * sc;
  }
  __syncthreads();
  int idx = blockIdx.x * 256 + t;                // < RR*128
  int c = idx & 127;
  out[idx] = fmaxf(0.f, fmaf(Yo[idx], scs[c], shs[c]));
}

// ---------------------------------------------------------------------------
extern "C" void kernel_launch(void* const* d_in, const int* in_sizes, int n_in,
                              void* d_out, int out_size, void* d_ws, size_t ws_size,
                              hipStream_t stream)
{
  const float* X    = (const float*)d_in[0];
  const float* STE  = (const float*)d_in[1];
  const float* Am   = (const float*)d_in[2];
  const float* Wq   = (const float*)d_in[3];
  const float* gq   = (const float*)d_in[5];
  const float* beq  = (const float*)d_in[6];
  const float* Wk   = (const float*)d_in[7];
  const float* gk   = (const float*)d_in[9];
  const float* bek  = (const float*)d_in[10];
  const float* Wv   = (const float*)d_in[11];
  const float* gv   = (const float*)d_in[13];
  const float* bev  = (const float*)d_in[14];
  const float* Wo   = (const float*)d_in[15];
  const float* go   = (const float*)d_in[17];
  const float* beo  = (const float*)d_in[18];
  // biases d_in[4,8,12,16] unused: BN subtracts batch mean -> bias cancels.

  char* ws = (char*)d_ws;
  bf16*  Yqkv = (bf16*)(ws + 0);            // 37,748,736
  float* Yo   = (float*)(ws + 0);           // aliases Yqkv (dead after attn)
  bf16*  Xb   = (bf16*)(ws + 50331648);     // 25,165,824 — aliases Kh/Vt:
                                            //   dead before k_norm_kv runs
  bf16*  Kh   = (bf16*)(ws + 50331648);
  bf16*  Vt   = (bf16*)(ws + 62914560);
  bf16*  AO   = (bf16*)(ws + 75497472);
  bf16*  Wtq  = (bf16*)(ws + 88080384);     // 196,608
  bf16*  Wto  = (bf16*)(ws + 88276992);     // 32,768
  unsigned int* Amb = (unsigned int*)(ws + 88309760);  // 32,768
  float* st   = (float*)(ws + 88342528);    // 8 shards x 1024 floats (32 KB)

  k_prep<<<6656, 256, 0, stream>>>(Wq, Wk, Wv, Wo, Am, X, STE,
                                   Wtq, Wto, Amb, st, Xb);
  k_gemm_qkv<<<dim3(RR / 128, 3), 256, 0, stream>>>(Xb, Wtq, Yqkv, st);
  k_norm_kv<<<dim3(CQKV, 8), 256, 0, stream>>>(Yqkv, st, gk, bek, gv, bev,
                                               Kh, Vt);
  k_attn<<<768, 256, 0, stream>>>(Yqkv, st, gq, beq, Kh, Vt, Amb, AO);
  k_gemm_o<<<RR / 128, 256, 0, stream>>>(AO, Wto, Yo, st);
  k_norm_o<<<(RR * 128) / 256, 256, 0, stream>>>(Yo, st, go, beo, (float*)d_out);
}